// Round 13
// baseline (499.145 us; speedup 1.0000x reference)
//
#include <hip/hip_runtime.h>

#define NFULL 8192
#define BATCH 4

typedef unsigned long long u64;
typedef unsigned int u32;
typedef __attribute__((ext_vector_type(8))) short bf8_t;   // 8 bf16 (4 VGPRs)
typedef __attribute__((ext_vector_type(4))) float f4_t;    // MFMA C/D

__device__ __forceinline__ u32 fbias(float f) {
  u32 u = __float_as_uint(f);
  return (u & 0x80000000u) ? ~u : (u | 0x80000000u);
}
__device__ __forceinline__ float funbias(u32 b) {
  u32 u = (b & 0x80000000u) ? (b & 0x7fffffffu) : ~b;
  return __uint_as_float(u);
}
__device__ __forceinline__ short f2bf(float f) {
  u32 u = __float_as_uint(f);
  u32 r = u + 0x7FFFu + ((u >> 16) & 1u);
  return (short)(r >> 16);
}

// ------------------------------------------------ fused grid build (both) --
__global__ __launch_bounds__(256) void build_grids_kernel(
    const float* __restrict__ pos, float4* __restrict__ sortedA,
    int* __restrict__ csA, float4* __restrict__ sortedB, int* __restrict__ csB) {
  __shared__ int cnt[4096];
  __shared__ int partial[256];
  int which = blockIdx.y, b = blockIdx.x, t = threadIdx.x;
  int NREF = which ? 2048 : 8192;
  int GR = which ? 8 : 16;
  int NC = GR * GR * GR;
  float4* sorted = (which ? sortedB : sortedA) + (size_t)b * NREF;
  int* cs = (which ? csB : csA) + b * (which ? 513 : 4097);
  const float* pb = pos + (size_t)b * NFULL * 3;
  for (int c = t; c < NC; c += 256) cnt[c] = 0;
  __syncthreads();
  for (int p = t; p < NREF; p += 256) {
    float x = pb[p * 3 + 0], y = pb[p * 3 + 1], z = pb[p * 3 + 2];
    int cx = min(max((int)(x * GR), 0), GR - 1);
    int cy = min(max((int)(y * GR), 0), GR - 1);
    int cz = min(max((int)(z * GR), 0), GR - 1);
    atomicAdd(&cnt[(cz * GR + cy) * GR + cx], 1);
  }
  __syncthreads();
  int chunk = (NC + 255) / 256;
  int s = 0;
  for (int i = 0; i < chunk; ++i) {
    int c = t * chunk + i;
    if (c < NC) s += cnt[c];
  }
  partial[t] = s;
  __syncthreads();
  if (t == 0) {
    int run = 0;
    for (int i = 0; i < 256; ++i) { int v = partial[i]; partial[i] = run; run += v; }
  }
  __syncthreads();
  int run = partial[t];
  for (int i = 0; i < chunk; ++i) {
    int c = t * chunk + i;
    if (c < NC) { int v = cnt[c]; cnt[c] = run; run += v; }
  }
  __syncthreads();
  for (int c = t; c < NC; c += 256) cs[c] = cnt[c];
  if (t == 0) cs[NC] = NREF;
  __syncthreads();
  for (int p = t; p < NREF; p += 256) {
    float x = pb[p * 3 + 0], y = pb[p * 3 + 1], z = pb[p * 3 + 2];
    int cx = min(max((int)(x * GR), 0), GR - 1);
    int cy = min(max((int)(y * GR), 0), GR - 1);
    int cz = min(max((int)(z * GR), 0), GR - 1);
    int slot = atomicAdd(&cnt[(cz * GR + cy) * GR + cx], 1);
    sorted[slot] = make_float4(x, y, z, __uint_as_float((u32)p));
  }
}

// --------------------------------------------------- grouped insert core ---
template<int SL>
__device__ __forceinline__ void group_insert(u32 m16, u64 ck, int slot,
                                             u64& val, u64& tau) {
  if (m16) {
    while (m16) {
      int src = __ffs(m16) - 1;
      m16 &= m16 - 1;
      u64 c = __shfl((unsigned long long)ck, src, 16);
      u64 prev = __shfl_up((unsigned long long)val, 1, SL);
      if (slot == 0) prev = 0ull;
      val = (val <= c) ? val : ((prev <= c) ? c : prev);
    }
    tau = __shfl((unsigned long long)val, SL - 1, SL);
  }
}

// --------------------------------------- kNN grid, FLAT (NROW <= 16) -------
// R13: ADAPTIVE R — edge/corner queries (>=2 wall dims) get R+1, so their
// margin bound grows ((R+1)h)^2 and the full-scan fallback becomes a true
// Poisson-tail event instead of systematic (R12's 23%-occupancy stragglers).
// nrow worst case: 2 clipped dims (range 3) x 1 unclipped (range 5) = 15.
template<int SL, int KOUT, int GR, int RB, int NREF>
__global__ __launch_bounds__(256) void knn_grid_flat_kernel(
    const float* __restrict__ pos, const float4* __restrict__ sorted,
    const int* __restrict__ cellStart, int csStride, int Mq,
    int* __restrict__ oidx, float* __restrict__ od2) {
  int b = blockIdx.y;
  int wv = threadIdx.x >> 6, lane = threadIdx.x & 63;
  int g = lane >> 4, gl = lane & 15;
  int q = blockIdx.x * 16 + wv * 4 + g;
  const float* pb = pos + (size_t)b * NFULL * 3;
  const float4* sb = sorted + (size_t)b * NREF;
  const int* cs = cellStart + b * csStride;
  float qx = pb[q * 3 + 0], qy = pb[q * 3 + 1], qz = pb[q * 3 + 2];
  float qq = qx * qx + qy * qy + qz * qz;
  int ix = min(max((int)(qx * GR), 0), GR - 1);
  int iy = min(max((int)(qy * GR), 0), GR - 1);
  int iz = min(max((int)(qz * GR), 0), GR - 1);
  int wall = (ix == 0 || ix == GR - 1) + (iy == 0 || iy == GR - 1) +
             (iz == 0 || iz == GR - 1);
  int R = RB + (wall >= 2 ? 1 : 0);
  int x0 = max(ix - R, 0), x1 = min(ix + R, GR - 1);
  int y0 = max(iy - R, 0), y1 = min(iy + R, GR - 1);
  int z0 = max(iz - R, 0), z1 = min(iz + R, GR - 1);

  int ny = y1 - y0 + 1;
  int nrow = (z1 - z0 + 1) * ny;  // <= 15 (see header comment)
  int s_i = 0, len_i = 0;
  if (gl < nrow) {
    int zz = z0 + gl / ny, yy = y0 + gl % ny;
    int c0 = (zz * GR + yy) * GR + x0;
    s_i = cs[c0];
    len_i = cs[c0 + (x1 - x0) + 1] - s_i;
  }
  int p_i = len_i;
#pragma unroll
  for (int st = 1; st < 16; st <<= 1) {
    int o = __shfl_up(p_i, st, 16);
    if (gl >= st) p_i += o;
  }
  int T = __shfl(p_i, 15, 16);
  p_i -= len_i;              // exclusive prefix
  int d_i = s_i - p_i;       // sorted index = v + d_row
  if (gl >= nrow) p_i = 0x7fffffff;

  int slot = gl & (SL - 1);
  u64 val = ~0ull, tau = ~0ull;

  for (int v0 = 0; v0 < T; v0 += 16) {  // T group-uniform
    int v = v0 + gl;
    int r = 0;
#pragma unroll
    for (int st = 8; st >= 1; st >>= 1) {
      int pc = __shfl(p_i, r + st, 16);
      if (v >= pc) r += st;
    }
    int addr = v + __shfl(d_i, r, 16);
    u64 ck = ~0ull;
    if (v < T) {
      float4 P = sb[addr];
      float rr = P.x * P.x + P.y * P.y + P.z * P.z;
      float d2 = qq + rr - 2.0f * (qx * P.x + qy * P.y + qz * P.z);
      ck = ((u64)fbias(d2) << 32) | (u32)__float_as_uint(P.w);
    }
    u64 full = __ballot(ck < tau);
    u32 m16 = (u32)((full >> (g * 16)) & 0xFFFFull);
    group_insert<SL>(m16, ck, slot, val, tau);
  }

  const float h = 1.0f / GR;
  float m = 1e30f;
  if (x0 > 0)      m = fminf(m, qx - x0 * h);
  if (x1 < GR - 1) m = fminf(m, (x1 + 1) * h - qx);
  if (y0 > 0)      m = fminf(m, qy - y0 * h);
  if (y1 < GR - 1) m = fminf(m, (y1 + 1) * h - qy);
  if (z0 > 0)      m = fminf(m, qz - z0 * h);
  if (z1 < GR - 1) m = fminf(m, (z1 + 1) * h - qz);
  float bound = m * m;
  float tau_d2 = funbias((u32)(tau >> 32));
  if (!(tau_d2 < bound)) {  // group-uniform; now rare
    for (int t0 = 0; t0 < NREF; t0 += 16) {
      int j = t0 + gl;
      u64 ck = ~0ull;
      if (j < NREF) {
        float4 P = sb[j];
        int cx = min(max((int)(P.x * GR), 0), GR - 1);
        int cy = min(max((int)(P.y * GR), 0), GR - 1);
        int cz = min(max((int)(P.z * GR), 0), GR - 1);
        bool inbox = (cx >= x0 && cx <= x1 && cy >= y0 && cy <= y1 &&
                      cz >= z0 && cz <= z1);
        if (!inbox) {
          float rr = P.x * P.x + P.y * P.y + P.z * P.z;
          float d2 = qq + rr - 2.0f * (qx * P.x + qy * P.y + qz * P.z);
          ck = ((u64)fbias(d2) << 32) | (u32)__float_as_uint(P.w);
        }
      }
      u64 full = __ballot(ck < tau);
      u32 m16 = (u32)((full >> (g * 16)) & 0xFFFFull);
      group_insert<SL>(m16, ck, slot, val, tau);
    }
  }

  if (gl < KOUT) {
    size_t base = ((size_t)b * Mq + q) * KOUT;
    oidx[base + gl] = (int)(u32)val;
    od2[base + gl] = fmaxf(funbias((u32)(val >> 32)), 0.0f);
  }
}

// --------------------------------------- kNN grid, ROWS (NROW <= 32) -------
// R13: adaptive R (wall>=2 dims => R+1). nrow worst: clipped dims (ix==0 or
// GR-1, range <= RB+2) x one unclipped (range 2RB+3): RB=2 => 4x7=28 <= 32.
template<int SL, int KOUT, int GR, int RB, int NREF>
__global__ __launch_bounds__(256) void knn_grid_rows_kernel(
    const float* __restrict__ pos, const float4* __restrict__ sorted,
    const int* __restrict__ cellStart, int csStride, int Mq,
    int* __restrict__ oidx, float* __restrict__ od2) {
  int b = blockIdx.y;
  int wv = threadIdx.x >> 6, lane = threadIdx.x & 63;
  int g = lane >> 4, gl = lane & 15;
  int q = blockIdx.x * 16 + wv * 4 + g;
  const float* pb = pos + (size_t)b * NFULL * 3;
  const float4* sb = sorted + (size_t)b * NREF;
  const int* cs = cellStart + b * csStride;
  float qx = pb[q * 3 + 0], qy = pb[q * 3 + 1], qz = pb[q * 3 + 2];
  float qq = qx * qx + qy * qy + qz * qz;
  int ix = min(max((int)(qx * GR), 0), GR - 1);
  int iy = min(max((int)(qy * GR), 0), GR - 1);
  int iz = min(max((int)(qz * GR), 0), GR - 1);
  int wall = (ix == 0 || ix == GR - 1) + (iy == 0 || iy == GR - 1) +
             (iz == 0 || iz == GR - 1);
  int R = RB + (wall >= 2 ? 1 : 0);
  int x0 = max(ix - R, 0), x1 = min(ix + R, GR - 1);
  int y0 = max(iy - R, 0), y1 = min(iy + R, GR - 1);
  int z0 = max(iz - R, 0), z1 = min(iz + R, GR - 1);

  int ny = y1 - y0 + 1;
  int nrow = (z1 - z0 + 1) * ny;  // <= 28
  int sLo = 0, eLo = 0, sHi = 0, eHi = 0;
  if (gl < nrow) {
    int zz = z0 + gl / ny, yy = y0 + gl % ny;
    int c0 = (zz * GR + yy) * GR + x0;
    sLo = cs[c0]; eLo = cs[c0 + (x1 - x0) + 1];
  }
  {
    int i2 = gl + 16;
    if (i2 < nrow) {
      int zz = z0 + i2 / ny, yy = y0 + i2 % ny;
      int c0 = (zz * GR + yy) * GR + x0;
      sHi = cs[c0]; eHi = cs[c0 + (x1 - x0) + 1];
    }
  }

  int slot = gl & (SL - 1);
  u64 val = ~0ull, tau = ~0ull;

  for (int r = 0; r < nrow; ++r) {  // r group-uniform
    int sa = __shfl(sLo, r & 15, 16);
    int sb2 = __shfl(sHi, r & 15, 16);
    int ea = __shfl(eLo, r & 15, 16);
    int eb = __shfl(eHi, r & 15, 16);
    int s = (r < 16) ? sa : sb2;
    int e = (r < 16) ? ea : eb;
    for (int t0 = s; t0 < e; t0 += 16) {
      int j = t0 + gl;
      u64 ck = ~0ull;
      if (j < e) {
        float4 P = sb[j];
        float rr = P.x * P.x + P.y * P.y + P.z * P.z;
        float d2 = qq + rr - 2.0f * (qx * P.x + qy * P.y + qz * P.z);
        ck = ((u64)fbias(d2) << 32) | (u32)__float_as_uint(P.w);
      }
      u64 full = __ballot(ck < tau);
      u32 m16 = (u32)((full >> (g * 16)) & 0xFFFFull);
      group_insert<SL>(m16, ck, slot, val, tau);
    }
  }

  const float h = 1.0f / GR;
  float m = 1e30f;
  if (x0 > 0)      m = fminf(m, qx - x0 * h);
  if (x1 < GR - 1) m = fminf(m, (x1 + 1) * h - qx);
  if (y0 > 0)      m = fminf(m, qy - y0 * h);
  if (y1 < GR - 1) m = fminf(m, (y1 + 1) * h - qy);
  if (z0 > 0)      m = fminf(m, qz - z0 * h);
  if (z1 < GR - 1) m = fminf(m, (z1 + 1) * h - qz);
  float bound = m * m;
  float tau_d2 = funbias((u32)(tau >> 32));
  if (!(tau_d2 < bound)) {
    for (int t0 = 0; t0 < NREF; t0 += 16) {
      int j = t0 + gl;
      u64 ck = ~0ull;
      if (j < NREF) {
        float4 P = sb[j];
        int cx = min(max((int)(P.x * GR), 0), GR - 1);
        int cy = min(max((int)(P.y * GR), 0), GR - 1);
        int cz = min(max((int)(P.z * GR), 0), GR - 1);
        bool inbox = (cx >= x0 && cx <= x1 && cy >= y0 && cy <= y1 &&
                      cz >= z0 && cz <= z1);
        if (!inbox) {
          float rr = P.x * P.x + P.y * P.y + P.z * P.z;
          float d2 = qq + rr - 2.0f * (qx * P.x + qy * P.y + qz * P.z);
          ck = ((u64)fbias(d2) << 32) | (u32)__float_as_uint(P.w);
        }
      }
      u64 full = __ballot(ck < tau);
      u32 m16 = (u32)((full >> (g * 16)) & 0xFFFFull);
      group_insert<SL>(m16, ck, slot, val, tau);
    }
  }

  if (gl < KOUT) {
    size_t base = ((size_t)b * Mq + q) * KOUT;
    oidx[base + gl] = (int)(u32)val;
    od2[base + gl] = fmaxf(funbias((u32)(val >> 32)), 0.0f);
  }
}

// -------------------------------------------------------- kNN (brute) ------
template<int SL, int KOUT>
__global__ __launch_bounds__(256) void knn_kernel(
    const float* __restrict__ pos, int Nref, int Mq,
    int* __restrict__ oidx, float* __restrict__ od2) {
  int b = blockIdx.y;
  int wv = threadIdx.x >> 6, lane = threadIdx.x & 63;
  int g = lane >> 4, gl = lane & 15;
  int q = blockIdx.x * 16 + wv * 4 + g;
  const float* pb = pos + (size_t)b * NFULL * 3;
  float qx = pb[q * 3 + 0], qy = pb[q * 3 + 1], qz = pb[q * 3 + 2];
  float qq = qx * qx + qy * qy + qz * qz;

  int slot = gl & (SL - 1);
  u64 val = ~0ull, tau = ~0ull;

  for (int t0 = 0; t0 < Nref; t0 += 16) {
    int j = t0 + gl;
    float rx = pb[j * 3 + 0];
    float ry = pb[j * 3 + 1];
    float rz = pb[j * 3 + 2];
    float rr = rx * rx + ry * ry + rz * rz;
    float d2 = qq + rr - 2.0f * (qx * rx + qy * ry + qz * rz);
    u64 ck = ((u64)fbias(d2) << 32) | (u32)j;
    u64 full = __ballot(ck < tau);
    u32 m16 = (u32)((full >> (g * 16)) & 0xFFFFull);
    group_insert<SL>(m16, ck, slot, val, tau);
  }

  if (gl < KOUT) {
    size_t base = ((size_t)b * Mq + q) * KOUT;
    oidx[base + gl] = (int)(u32)val;
    od2[base + gl] = fmaxf(funbias((u32)(val >> 32)), 0.0f);
  }
}

// ----------------------------------- fused weight packing + pos copy -------
__device__ __forceinline__ void pack_tile_rt(const float* __restrict__ W,
                                             short* __restrict__ outp,
                                             int KDIM, int N, int tile, int lane) {
  int NT = N >> 4;
  int kt = tile / NT, nt = tile - kt * NT;
  int n = nt * 16 + (lane & 15);
  int k0 = kt * 32 + (lane >> 4) * 8;
  bf8_t v;
#pragma unroll
  for (int j = 0; j < 8; ++j) {
    int k = k0 + j;
    v[j] = (k < KDIM) ? f2bf(W[(size_t)k * N + n]) : (short)0;
  }
  *(bf8_t*)(outp + ((size_t)tile * 64 + lane) * 8) = v;
}

__global__ __launch_bounds__(64) void pack_copy_all_kernel(
    const float* d0W1, short* d0W1p, const float* d0W2, short* d0W2p,
    const float* d1W1, short* d1W1p, const float* d1W2, short* d1W2p,
    const float* d2W1, short* d2W1p, const float* d2W2, short* d2W2p,
    const float* u2W, short* u2Wp, const float* fW1, short* fW1p,
    const float* fW2, short* fW2p,
    const float* pos, float* posOut) {
  int blk = blockIdx.x, lane = threadIdx.x;
  if      (blk < 8)    pack_tile_rt(d0W1, d0W1p, 6, 128, blk, lane);
  else if (blk < 40)   pack_tile_rt(d0W2, d0W2p, 128, 128, blk - 8, lane);
  else if (blk < 120)  pack_tile_rt(d1W1, d1W1p, 131, 256, blk - 40, lane);
  else if (blk < 248)  pack_tile_rt(d1W2, d1W2p, 256, 256, blk - 120, lane);
  else if (blk < 536)  pack_tile_rt(d2W1, d2W1p, 259, 512, blk - 248, lane);
  else if (blk < 1048) pack_tile_rt(d2W2, d2W2p, 512, 512, blk - 536, lane);
  else if (blk < 1088) pack_tile_rt(u2W, u2Wp, 134, 128, blk - 1048, lane);
  else if (blk < 1120) pack_tile_rt(fW1, fW1p, 128, 128, blk - 1088, lane);
  else if (blk < 1152) pack_tile_rt(fW2, fW2p, 128, 128, blk - 1120, lane);
  else {
    int base = (blk - 1152) * 256;
#pragma unroll
    for (int j = 0; j < 4; ++j) {
      int i = base + lane + j * 64;
      posOut[i] = pos[i];
    }
  }
}

// ----------------------------------------------------- down MLP (MFMA) -----
template<int FEAT, int CIN, int CHID, int FPAD, int WPB>
__global__ __launch_bounds__(64 * WPB) void down_mfma_kernel(
    const float* __restrict__ pos, const float* __restrict__ xin,
    const int* __restrict__ idx,
    const short* __restrict__ W1p, const float* __restrict__ b1,
    const short* __restrict__ W2p, const float* __restrict__ b2,
    float* __restrict__ out, int n, int nprev) {
  const int KT1 = FPAD / 32, NT1 = CHID / 16;
  const int KT2 = CHID / 32, NT2 = CHID / 16;
  __shared__ short sFeat[16][FPAD];
  __shared__ short sH1[16][CHID];
  __shared__ int sIdx[16];
  __shared__ float sCtr[3];
  int b = blockIdx.y, q = blockIdx.x;
  int lane = threadIdx.x & 63, wv = threadIdx.x >> 6;
  const float* pb = pos + (size_t)b * NFULL * 3;
  const float* xb = xin + (size_t)b * nprev * CIN;
  if (threadIdx.x < 16) sIdx[threadIdx.x] = idx[((size_t)b * n + q) * 16 + threadIdx.x];
  if (threadIdx.x < 3) sCtr[threadIdx.x] = pb[q * 3 + threadIdx.x];
  __syncthreads();
  for (int e = threadIdx.x; e < 16 * FPAD; e += 64 * WPB) {
    int k = e / FPAD, c = e % FPAD;
    float v = 0.f;
    if (c < 3) v = pb[sIdx[k] * 3 + c] - sCtr[c];
    else if (c < FEAT) v = xb[(size_t)sIdx[k] * CIN + (c - 3)];
    sFeat[k][c] = f2bf(v);
  }
  __syncthreads();

  int col = lane & 15, quad = lane >> 4;
  bf8_t afr[KT1];
#pragma unroll
  for (int kt = 0; kt < KT1; ++kt)
    afr[kt] = *(const bf8_t*)&sFeat[col][kt * 32 + quad * 8];
  const bf8_t* W1t = (const bf8_t*)W1p;
  for (int nt = 2 * wv; nt < NT1; nt += 2 * WPB) {
    float bb0 = b1[nt * 16 + col], bb1 = b1[nt * 16 + 16 + col];
    f4_t acc0 = {bb0, bb0, bb0, bb0}, acc1 = {bb1, bb1, bb1, bb1};
#pragma unroll
    for (int kt = 0; kt < KT1; ++kt) {
      bf8_t bf0 = W1t[(kt * NT1 + nt) * 64 + lane];
      bf8_t bf1 = W1t[(kt * NT1 + nt + 1) * 64 + lane];
      acc0 = __builtin_amdgcn_mfma_f32_16x16x32_bf16(afr[kt], bf0, acc0, 0, 0, 0);
      acc1 = __builtin_amdgcn_mfma_f32_16x16x32_bf16(afr[kt], bf1, acc1, 0, 0, 0);
    }
#pragma unroll
    for (int r = 0; r < 4; ++r) {
      sH1[quad * 4 + r][nt * 16 + col] = f2bf(fmaxf(acc0[r], 0.f));
      sH1[quad * 4 + r][nt * 16 + 16 + col] = f2bf(fmaxf(acc1[r], 0.f));
    }
  }
  __syncthreads();

  bf8_t afr2[KT2];
#pragma unroll
  for (int kt = 0; kt < KT2; ++kt)
    afr2[kt] = *(const bf8_t*)&sH1[col][kt * 32 + quad * 8];
  const bf8_t* W2t = (const bf8_t*)W2p;
  float* ob = out + ((size_t)b * n + q) * CHID;
  for (int nt = 2 * wv; nt < NT2; nt += 2 * WPB) {
    float bb0 = b2[nt * 16 + col], bb1 = b2[nt * 16 + 16 + col];
    f4_t acc0 = {bb0, bb0, bb0, bb0}, acc1 = {bb1, bb1, bb1, bb1};
#pragma unroll
    for (int kt = 0; kt < KT2; ++kt) {
      bf8_t bf0 = W2t[(kt * NT2 + nt) * 64 + lane];
      bf8_t bf1 = W2t[(kt * NT2 + nt + 1) * 64 + lane];
      acc0 = __builtin_amdgcn_mfma_f32_16x16x32_bf16(afr2[kt], bf0, acc0, 0, 0, 0);
      acc1 = __builtin_amdgcn_mfma_f32_16x16x32_bf16(afr2[kt], bf1, acc1, 0, 0, 0);
    }
    float m0 = fmaxf(fmaxf(acc0[0], acc0[1]), fmaxf(acc0[2], acc0[3]));
    float m1 = fmaxf(fmaxf(acc1[0], acc1[1]), fmaxf(acc1[2], acc1[3]));
    m0 = fmaxf(m0, __shfl_xor(m0, 16, 64));
    m0 = fmaxf(m0, __shfl_xor(m0, 32, 64));
    m1 = fmaxf(m1, __shfl_xor(m1, 16, 64));
    m1 = fmaxf(m1, __shfl_xor(m1, 32, 64));
    if (lane < 16) {
      ob[nt * 16 + lane] = m0;
      ob[nt * 16 + 16 + lane] = m1;
    }
  }
}

// --------------------------------------------------------------- up MLP ----
template<int CIN, int CPRV, int COUT, int TP>
__global__ __launch_bounds__(COUT) void up_kernel(
    const float* __restrict__ xc, int ncoarse,
    const int* __restrict__ idx3, const float* __restrict__ d23,
    const float* __restrict__ prv, const float* __restrict__ W,
    const float* __restrict__ bvec, float* __restrict__ out, int m) {
  const int CTOT = CIN + CPRV;
  __shared__ float sCat[TP][CTOT];
  __shared__ float sWt[TP][3];
  __shared__ int   sIt[TP][3];
  int b = blockIdx.y, q0 = blockIdx.x * TP, t = threadIdx.x;
  if (t < TP) {
    size_t base = ((size_t)b * m + q0 + t) * 3;
    float d0 = d23[base + 0], d1 = d23[base + 1], d2v = d23[base + 2];
    float w0 = 1.f / (d0 + 1e-8f), w1 = 1.f / (d1 + 1e-8f), w2 = 1.f / (d2v + 1e-8f);
    float s = w0 + w1 + w2;
    sWt[t][0] = w0 / s; sWt[t][1] = w1 / s; sWt[t][2] = w2 / s;
    sIt[t][0] = idx3[base + 0]; sIt[t][1] = idx3[base + 1]; sIt[t][2] = idx3[base + 2];
  }
  __syncthreads();
  const float* xb = xc + (size_t)b * ncoarse * CIN;
  const float* pvb = prv + ((size_t)b * m + q0) * CPRV;
  for (int e = t; e < TP * CIN; e += COUT) {
    int p = e / CIN, c = e % CIN;
    sCat[p][c] = sWt[p][0] * xb[(size_t)sIt[p][0] * CIN + c]
               + sWt[p][1] * xb[(size_t)sIt[p][1] * CIN + c]
               + sWt[p][2] * xb[(size_t)sIt[p][2] * CIN + c];
  }
  for (int e = t; e < TP * CPRV; e += COUT) {
    int p = e / CPRV, c = e % CPRV;
    sCat[p][CIN + c] = pvb[(size_t)p * CPRV + c];
  }
  __syncthreads();
  float acc[TP];
  float bb = bvec[t];
#pragma unroll
  for (int p = 0; p < TP; ++p) acc[p] = bb;
  for (int c4 = 0; c4 < CTOT / 4; ++c4) {
    int c = 4 * c4;
    float w0 = W[(c + 0) * COUT + t];
    float w1 = W[(c + 1) * COUT + t];
    float w2 = W[(c + 2) * COUT + t];
    float w3 = W[(c + 3) * COUT + t];
#pragma unroll
    for (int p = 0; p < TP; ++p) {
      float4 v = *(const float4*)&sCat[p][c];
      acc[p] = fmaf(v.x, w0, acc[p]);
      acc[p] = fmaf(v.y, w1, acc[p]);
      acc[p] = fmaf(v.z, w2, acc[p]);
      acc[p] = fmaf(v.w, w3, acc[p]);
    }
  }
#pragma unroll
  for (int p = 0; p < TP; ++p)
    out[((size_t)b * m + q0 + p) * COUT + t] = fmaxf(acc[p], 0.f);
}

// ------------------------------------- fused up2 + final MLP (bf16 MFMA) ---
__global__ __launch_bounds__(128) void up2f_mfma_kernel(
    const float* __restrict__ xc,
    const int* __restrict__ idx3, const float* __restrict__ d23,
    const float* __restrict__ x0, const float* __restrict__ pos0,
    const short* __restrict__ u2Wp, const float* __restrict__ u2b,
    const short* __restrict__ fW1p, const float* __restrict__ fb1,
    const short* __restrict__ fW2p, const float* __restrict__ fb2,
    float* __restrict__ out) {
  __shared__ short sA[16][160];
  __shared__ short sB[16][128];
  __shared__ float sWt[16][3];
  __shared__ int   sIt[16][3];
  int b = blockIdx.y, q0 = blockIdx.x * 16, t = threadIdx.x;
  int lane = t & 63, wv = t >> 6;
  if (t < 16) {
    size_t base = ((size_t)b * NFULL + q0 + t) * 3;
    float d0 = d23[base + 0], d1 = d23[base + 1], d2v = d23[base + 2];
    float w0 = 1.f / (d0 + 1e-8f), w1 = 1.f / (d1 + 1e-8f), w2 = 1.f / (d2v + 1e-8f);
    float s = w0 + w1 + w2;
    sWt[t][0] = w0 / s; sWt[t][1] = w1 / s; sWt[t][2] = w2 / s;
    sIt[t][0] = idx3[base + 0]; sIt[t][1] = idx3[base + 1]; sIt[t][2] = idx3[base + 2];
  }
  __syncthreads();
  const float* xb = xc + (size_t)b * 2048 * 128;
#pragma unroll
  for (int p = 0; p < 16; ++p) {
    float v = sWt[p][0] * xb[(size_t)sIt[p][0] * 128 + t]
            + sWt[p][1] * xb[(size_t)sIt[p][1] * 128 + t]
            + sWt[p][2] * xb[(size_t)sIt[p][2] * 128 + t];
    sA[p][t] = f2bf(v);
  }
  for (int e = t; e < 16 * 32; e += 128) {
    int p = e / 32, c = 128 + (e % 32);
    float v = 0.f;
    if (c < 131) v = x0[((size_t)b * NFULL + q0 + p) * 3 + (c - 128)];
    else if (c < 134) v = pos0[((size_t)b * NFULL + q0 + p) * 3 + (c - 131)];
    sA[p][c] = f2bf(v);
  }
  __syncthreads();
  int col = lane & 15, quad = lane >> 4;

  bf8_t a1[5];
#pragma unroll
  for (int kt = 0; kt < 5; ++kt)
    a1[kt] = *(const bf8_t*)&sA[col][kt * 32 + quad * 8];
  const bf8_t* W1t = (const bf8_t*)u2Wp;
  for (int nt = 2 * wv; nt < 8; nt += 4) {
    float bb0 = u2b[nt * 16 + col], bb1 = u2b[nt * 16 + 16 + col];
    f4_t acc0 = {bb0, bb0, bb0, bb0}, acc1 = {bb1, bb1, bb1, bb1};
#pragma unroll
    for (int kt = 0; kt < 5; ++kt) {
      bf8_t bf0 = W1t[(kt * 8 + nt) * 64 + lane];
      bf8_t bf1 = W1t[(kt * 8 + nt + 1) * 64 + lane];
      acc0 = __builtin_amdgcn_mfma_f32_16x16x32_bf16(a1[kt], bf0, acc0, 0, 0, 0);
      acc1 = __builtin_amdgcn_mfma_f32_16x16x32_bf16(a1[kt], bf1, acc1, 0, 0, 0);
    }
#pragma unroll
    for (int r = 0; r < 4; ++r) {
      sB[quad * 4 + r][nt * 16 + col] = f2bf(fmaxf(acc0[r], 0.f));
      sB[quad * 4 + r][nt * 16 + 16 + col] = f2bf(fmaxf(acc1[r], 0.f));
    }
  }
  __syncthreads();

  bf8_t a2[4];
#pragma unroll
  for (int kt = 0; kt < 4; ++kt)
    a2[kt] = *(const bf8_t*)&sB[col][kt * 32 + quad * 8];
  const bf8_t* W2t = (const bf8_t*)fW1p;
  for (int nt = 2 * wv; nt < 8; nt += 4) {
    float bb0 = fb1[nt * 16 + col], bb1 = fb1[nt * 16 + 16 + col];
    f4_t acc0 = {bb0, bb0, bb0, bb0}, acc1 = {bb1, bb1, bb1, bb1};
#pragma unroll
    for (int kt = 0; kt < 4; ++kt) {
      bf8_t bf0 = W2t[(kt * 8 + nt) * 64 + lane];
      bf8_t bf1 = W2t[(kt * 8 + nt + 1) * 64 + lane];
      acc0 = __builtin_amdgcn_mfma_f32_16x16x32_bf16(a2[kt], bf0, acc0, 0, 0, 0);
      acc1 = __builtin_amdgcn_mfma_f32_16x16x32_bf16(a2[kt], bf1, acc1, 0, 0, 0);
    }
#pragma unroll
    for (int r = 0; r < 4; ++r) {
      sA[quad * 4 + r][nt * 16 + col] = f2bf(fmaxf(acc0[r], 0.f));
      sA[quad * 4 + r][nt * 16 + 16 + col] = f2bf(fmaxf(acc1[r], 0.f));
    }
  }
  __syncthreads();

  bf8_t a3[4];
#pragma unroll
  for (int kt = 0; kt < 4; ++kt)
    a3[kt] = *(const bf8_t*)&sA[col][kt * 32 + quad * 8];
  const bf8_t* W3t = (const bf8_t*)fW2p;
  float* ob = out + ((size_t)b * NFULL + q0) * 128;
  for (int nt = 2 * wv; nt < 8; nt += 4) {
    float bb0 = fb2[nt * 16 + col], bb1 = fb2[nt * 16 + 16 + col];
    f4_t acc0 = {bb0, bb0, bb0, bb0}, acc1 = {bb1, bb1, bb1, bb1};
#pragma unroll
    for (int kt = 0; kt < 4; ++kt) {
      bf8_t bf0 = W3t[(kt * 8 + nt) * 64 + lane];
      bf8_t bf1 = W3t[(kt * 8 + nt + 1) * 64 + lane];
      acc0 = __builtin_amdgcn_mfma_f32_16x16x32_bf16(a3[kt], bf0, acc0, 0, 0, 0);
      acc1 = __builtin_amdgcn_mfma_f32_16x16x32_bf16(a3[kt], bf1, acc1, 0, 0, 0);
    }
#pragma unroll
    for (int r = 0; r < 4; ++r) {
      ob[(size_t)(quad * 4 + r) * 128 + nt * 16 + col] = acc0[r];
      ob[(size_t)(quad * 4 + r) * 128 + nt * 16 + 16 + col] = acc1[r];
    }
  }
}

// ------------------------------------------------------------------ launch -
extern "C" void kernel_launch(void* const* d_in, const int* in_sizes, int n_in,
                              void* d_out, int out_size, void* d_ws, size_t ws_size,
                              hipStream_t stream) {
  const float* x    = (const float*)d_in[0];
  const float* pos  = (const float*)d_in[1];
  const float* d0W1 = (const float*)d_in[2];
  const float* d0b1 = (const float*)d_in[3];
  const float* d0W2 = (const float*)d_in[4];
  const float* d0b2 = (const float*)d_in[5];
  const float* d1W1 = (const float*)d_in[6];
  const float* d1b1 = (const float*)d_in[7];
  const float* d1W2 = (const float*)d_in[8];
  const float* d1b2 = (const float*)d_in[9];
  const float* d2W1 = (const float*)d_in[10];
  const float* d2b1 = (const float*)d_in[11];
  const float* d2W2 = (const float*)d_in[12];
  const float* d2b2 = (const float*)d_in[13];
  const float* u0W  = (const float*)d_in[14];
  const float* u0b  = (const float*)d_in[15];
  const float* u1W  = (const float*)d_in[16];
  const float* u1b  = (const float*)d_in[17];
  const float* u2W  = (const float*)d_in[18];
  const float* u2b  = (const float*)d_in[19];
  const float* fW1  = (const float*)d_in[20];
  const float* fb1  = (const float*)d_in[21];
  const float* fW2  = (const float*)d_in[22];
  const float* fb2  = (const float*)d_in[23];

  char* ws = (char*)d_ws;
  float* x1    = (float*)(ws + 0);
  float* x2    = (float*)(ws + 4194304);
  float* x3    = (float*)(ws + 6291456);
  float* up0o  = (float*)(ws + 7340032);
  float* up1o  = (float*)(ws + 9437184);
  int*   idx0  = (int*)  (ws + 13631488);
  int*   idx1  = (int*)  (ws + 14155776);
  int*   idx2  = (int*)  (ws + 14286848);
  float* d2s   = (float*)(ws + 14319616);
  int*   idxu0 = (int*)  (ws + 14843904);
  float* d2u0  = (float*)(ws + 14868480);
  int*   idxu1 = (int*)  (ws + 14893056);
  float* d2u1  = (float*)(ws + 14991360);
  int*   idxu2 = (int*)  (ws + 15089664);
  float* d2u2  = (float*)(ws + 15482880);
  short* d1W1p = (short*)(ws + 15876096);
  short* d1W2p = (short*)(ws + 15958016);
  short* d2W1p = (short*)(ws + 16089088);
  short* d2W2p = (short*)(ws + 16384000);
  short* d0W1p = (short*)(ws + 16908288);
  short* d0W2p = (short*)(ws + 16916480);
  float4* sortedA = (float4*)(ws + 16949248);
  int*    csA     = (int*)   (ws + 17473536);
  float4* sortedB = (float4*)(ws + 17539136);
  int*    csB     = (int*)   (ws + 17670208);
  short* u2Wp  = (short*)(ws + 17697920);
  short* fW1p  = (short*)(ws + 17738880);
  short* fW2p  = (short*)(ws + 17771648);

  float* out = (float*)d_out;

  // ---- fused packing + pos passthrough; fused grid builds ----
  pack_copy_all_kernel<<<dim3(1536), 64, 0, stream>>>(
      d0W1, d0W1p, d0W2, d0W2p, d1W1, d1W1p, d1W2, d1W2p,
      d2W1, d2W1p, d2W2, d2W2p, u2W, u2Wp, fW1, fW1p, fW2, fW2p,
      pos, out + (size_t)BATCH * NFULL * 128);
  build_grids_kernel<<<dim3(BATCH, 2), 256, 0, stream>>>(pos, sortedA, csA, sortedB, csB);

  // ---- down path ----
  knn_grid_rows_kernel<16, 16, 16, 2, 8192><<<dim3(128, BATCH), 256, 0, stream>>>(
      pos, sortedA, csA, 4097, 2048, idx0, d2s);
  down_mfma_kernel<6, 3, 128, 32, 1><<<dim3(2048, BATCH), 64, 0, stream>>>(
      pos, x, idx0, d0W1p, d0b1, d0W2p, d0b2, x1, 2048, 8192);
  knn_grid_rows_kernel<16, 16, 8, 2, 2048><<<dim3(32, BATCH), 256, 0, stream>>>(
      pos, sortedB, csB, 513, 512, idx1, d2s);
  down_mfma_kernel<131, 128, 256, 160, 1><<<dim3(512, BATCH), 64, 0, stream>>>(
      pos, x1, idx1, d1W1p, d1b1, d1W2p, d1b2, x2, 512, 2048);
  knn_kernel<16, 16><<<dim3(8, BATCH), 256, 0, stream>>>(pos, 512, 128, idx2, d2s);
  down_mfma_kernel<259, 256, 512, 288, 2><<<dim3(128, BATCH), 128, 0, stream>>>(
      pos, x2, idx2, d2W1p, d2b1, d2W2p, d2b2, x3, 128, 512);

  // ---- up path ----
  knn_kernel<4, 3><<<dim3(32, BATCH), 256, 0, stream>>>(pos, 128, 512, idxu0, d2u0);
  up_kernel<512, 256, 256, 8><<<dim3(64, BATCH), 256, 0, stream>>>(
      x3, 128, idxu0, d2u0, x2, u0W, u0b, up0o, 512);
  knn_kernel<4, 3><<<dim3(128, BATCH), 256, 0, stream>>>(pos, 512, 2048, idxu1, d2u1);
  up_kernel<256, 128, 128, 16><<<dim3(128, BATCH), 128, 0, stream>>>(
      up0o, 512, idxu1, d2u1, x1, u1W, u1b, up1o, 2048);
  knn_grid_flat_kernel<4, 3, 8, 1, 2048><<<dim3(512, BATCH), 256, 0, stream>>>(
      pos, sortedB, csB, 513, 8192, idxu2, d2u2);
  up2f_mfma_kernel<<<dim3(512, BATCH), 128, 0, stream>>>(
      up1o, idxu2, d2u2, x, pos, u2Wp, u2b, fW1p, fb1, fW2p, fb2, out);
}